// Round 5
// baseline (705.545 us; speedup 1.0000x reference)
//
#include <hip/hip_runtime.h>
#include <math.h>

// ---------------------------------------------------------------------------
// HeteroGNN forward. bf16 MFMA GEMM (B-in-registers, A from global, no LDS),
// bf16 projected features, CSR mean-agg with fused BN-stat partials,
// hierarchical parallel scan, bf16 final features, pure-copy widening gather.
//   Wf (192 x F) = [ 0.5*(Wul0@Wd0 + Wul1@Wd1) ; 0.5*Wur0@Ws0 ; 0.5*Wur1@Ws1 ]
//   [h | P0 | P1] = x @ Wf^T   (h fp32, P bf16)
//   h[d] += mean_{csr0[d]} P0[src] + mean_{csr1[d]} P1[src]  (+ BN partials)
//   BN(train, eps=1, biased) + LeakyReLU(0.01) -> bf16
// ---------------------------------------------------------------------------

typedef float f32x4 __attribute__((ext_vector_type(4)));
typedef float f32x2 __attribute__((ext_vector_type(2)));
typedef short bf16x8 __attribute__((ext_vector_type(8)));
typedef unsigned short u16x4 __attribute__((ext_vector_type(4)));
typedef unsigned short u16x8 __attribute__((ext_vector_type(8)));

#define NB_SCAN 64   // scan blocks per edge type
#define NB_AGG 512   // agg blocks (pbuf rows)

static __device__ __forceinline__ unsigned short f2bf(float f) {
  unsigned int u = __builtin_bit_cast(unsigned int, f);
  unsigned int r = (u + 0x7FFFu + ((u >> 16) & 1u)) >> 16;
  return (unsigned short)r;
}
static __device__ __forceinline__ float bfl(unsigned int u) {
  return __builtin_bit_cast(float, u << 16);
}
static __device__ __forceinline__ float bfh(unsigned int u) {
  return __builtin_bit_cast(float, u & 0xFFFF0000u);
}

__global__ void zero_cnt(int* __restrict__ cnt0, int* __restrict__ cnt1, int N) {
  int g = blockIdx.x * 256 + threadIdx.x;
  if (g < N) { cnt0[g] = 0; cnt1[g] = 0; }
}

// cvt x->bf16 (blocks [0, cvtB)), fusew1 (next 96), fusew2 (next 48)
__global__ void prep_kernel(const float* __restrict__ x, unsigned short* __restrict__ xb,
                            int n4, int cvtB,
                            const float* __restrict__ Wd10, const float* __restrict__ Ws10,
                            const float* __restrict__ Wu10, const float* __restrict__ Wd11,
                            const float* __restrict__ Ws11, const float* __restrict__ Wu11,
                            unsigned short* __restrict__ Wfb1,
                            const float* __restrict__ Wd20, const float* __restrict__ Ws20,
                            const float* __restrict__ Wu20, const float* __restrict__ Wd21,
                            const float* __restrict__ Ws21, const float* __restrict__ Wu21,
                            unsigned short* __restrict__ Wfb2) {
  int b = blockIdx.x;
  if (b < cvtB) {
    int g = b * 256 + threadIdx.x;
    if (g >= n4) return;
    f32x4 v = ((const f32x4*)x)[g];
    u16x4 o;
#pragma unroll
    for (int j = 0; j < 4; ++j) o[j] = f2bf(v[j]);
    ((u16x4*)xb)[g] = o;
    return;
  }
  const float *Wd0, *Ws0, *Wu0, *Wd1, *Ws1, *Wu1;
  unsigned short* Wfb;
  int K, gid;
  if (b < cvtB + 96) {
    Wd0 = Wd10; Ws0 = Ws10; Wu0 = Wu10; Wd1 = Wd11; Ws1 = Ws11; Wu1 = Wu11;
    Wfb = Wfb1; K = 128;
    gid = (b - cvtB) * 256 + threadIdx.x;
  } else {
    Wd0 = Wd20; Ws0 = Ws20; Wu0 = Wu20; Wd1 = Wd21; Ws1 = Ws21; Wu1 = Wu21;
    Wfb = Wfb2; K = 64;
    gid = (b - cvtB - 96) * 256 + threadIdx.x;
  }
  if (gid >= 192 * K) return;
  int i = gid / K, j = gid - i * K;
  float s = 0.f;
  if (i < 64) {
#pragma unroll 4
    for (int k = 0; k < 64; ++k)
      s += Wu0[i * 128 + k] * Wd0[k * K + j] + Wu1[i * 128 + k] * Wd1[k * K + j];
  } else if (i < 128) {
    int ii = i - 64;
#pragma unroll 4
    for (int k = 0; k < 64; ++k) s += Wu0[ii * 128 + 64 + k] * Ws0[k * K + j];
  } else {
    int ii = i - 128;
#pragma unroll 4
    for (int k = 0; k < 64; ++k) s += Wu1[ii * 128 + 64 + k] * Ws1[k * K + j];
  }
  Wfb[gid] = f2bf(0.5f * s);
}

__global__ void count_both(const int* __restrict__ dst0, const int* __restrict__ dst1,
                           int* __restrict__ cnt0, int* __restrict__ cnt1, int E, int eg) {
  int b = blockIdx.x;
  bool t1 = b >= eg;
  int e = (t1 ? b - eg : b) * 256 + threadIdx.x;
  if (e >= E) return;
  if (t1) atomicAdd(&cnt1[dst1[e]], 1);
  else atomicAdd(&cnt0[dst0[e]], 1);
}

// scan stage A: per-block sums. 2*NB_SCAN blocks.
__global__ __launch_bounds__(256) void scanA(const int* __restrict__ cnt0,
                                             const int* __restrict__ cnt1,
                                             int* __restrict__ bsum, int N, int chunk) {
  int b = blockIdx.x;
  const int* cnt = (b < NB_SCAN) ? cnt0 : cnt1;
  int lb = (b < NB_SCAN) ? b : b - NB_SCAN;
  int lo = lb * chunk, hi = min(lo + chunk, N);
  int s = 0;
  for (int i = lo + threadIdx.x; i < hi; i += 256) s += cnt[i];
  __shared__ int red[256];
  red[threadIdx.x] = s;
  __syncthreads();
  for (int off = 128; off > 0; off >>= 1) {
    if (threadIdx.x < off) red[threadIdx.x] += red[threadIdx.x + off];
    __syncthreads();
  }
  if (threadIdx.x == 0) bsum[b] = red[0];
}

// scan stage B: exclusive scan of bsum per type. 1 block, 128 threads.
__global__ void scanB(const int* __restrict__ bsum, int* __restrict__ bbase) {
  __shared__ int l[2 * NB_SCAN];
  int t = threadIdx.x;
  int v0 = bsum[t];
  l[t] = v0;
  __syncthreads();
  for (int off = 1; off < NB_SCAN; off <<= 1) {
    int v = l[t];
    if ((t & (NB_SCAN - 1)) >= off) v += l[t - off];
    __syncthreads();
    l[t] = v;
    __syncthreads();
  }
  bbase[t] = l[t] - v0;
}

// scan stage C: per-block local exclusive scan + write base. 2*NB_SCAN blocks.
__global__ __launch_bounds__(256) void scanC(const int* __restrict__ cnt0,
                                             const int* __restrict__ cnt1,
                                             const int* __restrict__ bbase,
                                             int* __restrict__ base0, int* __restrict__ base1,
                                             int N, int chunk, int E) {
  int b = blockIdx.x;
  const int* cnt = (b < NB_SCAN) ? cnt0 : cnt1;
  int* base = (b < NB_SCAN) ? base0 : base1;
  int lb = (b < NB_SCAN) ? b : b - NB_SCAN;
  int lo = lb * chunk, hi = min(lo + chunk, N);
  int t = threadIdx.x;
  int v[4];
  int ls = 0;
  int i0 = lo + t * 4;
#pragma unroll
  for (int j = 0; j < 4; ++j) {
    v[j] = (i0 + j < hi) ? cnt[i0 + j] : 0;
    ls += v[j];
  }
  __shared__ int l[256];
  l[t] = ls;
  __syncthreads();
  for (int off = 1; off < 256; off <<= 1) {
    int x = l[t];
    if (t >= off) x += l[t - off];
    __syncthreads();
    l[t] = x;
    __syncthreads();
  }
  int run = bbase[b] + l[t] - ls;
#pragma unroll
  for (int j = 0; j < 4; ++j) {
    if (i0 + j < hi) base[i0 + j] = run;
    run += v[j];
  }
  if (t == 0 && lb == NB_SCAN - 1) base[N] = E;
}

__global__ void fill_both(const int* __restrict__ src0, const int* __restrict__ dst0,
                          const int* __restrict__ base0, int* __restrict__ cnt0,
                          int* __restrict__ csr0,
                          const int* __restrict__ src1, const int* __restrict__ dst1,
                          const int* __restrict__ base1, int* __restrict__ cnt1,
                          int* __restrict__ csr1, int E, int eg) {
  int b = blockIdx.x;
  bool t1 = b >= eg;
  int e = (t1 ? b - eg : b) * 256 + threadIdx.x;
  if (e >= E) return;
  const int* src = t1 ? src1 : src0;
  const int* dst = t1 ? dst1 : dst0;
  const int* base = t1 ? base1 : base0;
  int* cnt = t1 ? cnt1 : cnt0;
  int* csr = t1 ? csr1 : csr0;
  int d = dst[e];
  int p = atomicSub(&cnt[d], 1) - 1;
  csr[base[d] + p] = src[e];
}

// [h|P0|P1] = xb[N,K](bf16) @ Wfb[192,K]^T(bf16). 64 rows/block, 4 waves x 48 cols.
template <int K>
__global__ __launch_bounds__(256) void mm_mfma(const unsigned short* __restrict__ xb,
                                               const unsigned short* __restrict__ Wfb,
                                               float* __restrict__ h,
                                               unsigned short* __restrict__ P0,
                                               unsigned short* __restrict__ P1, int N) {
  constexpr int NKS = K / 32;
  int tid = threadIdx.x;
  int l = tid & 63;
  int wv = tid >> 6;
  int lr = l & 15;
  int lj = l >> 4;
  int brow = blockIdx.x * 64;
  int wcol = wv * 48;

  bf16x8 B[3 * NKS];
#pragma unroll
  for (int ct = 0; ct < 3; ++ct)
#pragma unroll
    for (int ks = 0; ks < NKS; ++ks) {
      int col = wcol + ct * 16 + lr;
      B[ct * NKS + ks] = *(const bf16x8*)&Wfb[(size_t)col * K + ks * 32 + lj * 8];
    }

  f32x4 acc[4][3];
#pragma unroll
  for (int rt = 0; rt < 4; ++rt)
#pragma unroll
    for (int ct = 0; ct < 3; ++ct) acc[rt][ct] = (f32x4){0.f, 0.f, 0.f, 0.f};

#pragma unroll
  for (int ks = 0; ks < NKS; ++ks) {
    bf16x8 A[4];
#pragma unroll
    for (int rt = 0; rt < 4; ++rt) {
      int row = brow + rt * 16 + lr;
      if (row >= N) row = N - 1;
      A[rt] = *(const bf16x8*)&xb[(size_t)row * K + ks * 32 + lj * 8];
    }
#pragma unroll
    for (int rt = 0; rt < 4; ++rt)
#pragma unroll
      for (int ct = 0; ct < 3; ++ct)
        acc[rt][ct] =
            __builtin_amdgcn_mfma_f32_16x16x32_bf16(A[rt], B[ct * NKS + ks], acc[rt][ct], 0, 0, 0);
  }

#pragma unroll
  for (int rt = 0; rt < 4; ++rt)
#pragma unroll
    for (int ct = 0; ct < 3; ++ct) {
      int gct = (wcol >> 4) + ct;
      int sel = gct >> 2;
      int c0 = (gct & 3) * 16 + lr;
#pragma unroll
      for (int r = 0; r < 4; ++r) {
        int row = brow + rt * 16 + lj * 4 + r;
        if (row < N) {
          if (sel == 0) h[(size_t)row * 64 + c0] = acc[rt][ct][r];
          else if (sel == 1) P0[(size_t)row * 64 + c0] = f2bf(acc[rt][ct][r]);
          else P1[(size_t)row * 64 + c0] = f2bf(acc[rt][ct][r]);
        }
      }
    }
}

// half-wave (32 lanes, 2 ch/lane) per node, grid-stride; fused BN partial sums.
__global__ __launch_bounds__(256) void agg_kernel(float* __restrict__ h,
                                                  const unsigned short* __restrict__ P0,
                                                  const unsigned short* __restrict__ P1,
                                                  const int* __restrict__ csr0,
                                                  const int* __restrict__ base0,
                                                  const int* __restrict__ csr1,
                                                  const int* __restrict__ base1, int N,
                                                  float* __restrict__ pbuf) {
  int tid = threadIdx.x;
  int c = tid & 31;   // channel pair (2c, 2c+1)
  int slot = tid >> 5;  // 0..7
  int co = 2 * c;
  float t0 = 0.f, t1 = 0.f, q0 = 0.f, q1 = 0.f;  // BN partials
  for (int w = blockIdx.x * 8 + slot; w < N; w += NB_AGG * 8) {
    float a0, a1;
    // type 0
    int i = base0[w], e0 = base0[w + 1];
    int n0 = e0 - i;
    a0 = 0.f; a1 = 0.f;
    int nidx = (i < e0) ? csr0[i] : 0;
    while (i < e0) {
      int idx = nidx;
      ++i;
      nidx = (i < e0) ? csr0[i] : 0;
      unsigned int u = *(const unsigned int*)&P0[(size_t)idx * 64 + co];
      a0 += bfl(u);
      a1 += bfh(u);
    }
    float iv = 1.0f / fmaxf((float)n0, 1.0f);
    float s0 = a0 * iv, s1 = a1 * iv;
    // type 1
    i = base1[w];
    int e1 = base1[w + 1];
    int n1 = e1 - i;
    a0 = 0.f; a1 = 0.f;
    nidx = (i < e1) ? csr1[i] : 0;
    while (i < e1) {
      int idx = nidx;
      ++i;
      nidx = (i < e1) ? csr1[i] : 0;
      unsigned int u = *(const unsigned int*)&P1[(size_t)idx * 64 + co];
      a0 += bfl(u);
      a1 += bfh(u);
    }
    iv = 1.0f / fmaxf((float)n1, 1.0f);
    s0 += a0 * iv;
    s1 += a1 * iv;
    f32x2* hp = (f32x2*)&h[(size_t)w * 64 + co];
    f32x2 hv = *hp;
    hv.x += s0;
    hv.y += s1;
    *hp = hv;
    t0 += hv.x; q0 += hv.x * hv.x;
    t1 += hv.y; q1 += hv.y * hv.y;
  }
  __shared__ float red[8 * 32 * 4];
  int ri = slot * 128 + c * 4;
  red[ri] = t0; red[ri + 1] = t1; red[ri + 2] = q0; red[ri + 3] = q1;
  __syncthreads();
  if (tid < 64) {
    int ch = tid;           // 0..63
    int cc = ch >> 1;       // pair index
    int hl = ch & 1;        // which of the pair
    float s = 0.f, s2 = 0.f;
#pragma unroll
    for (int sl = 0; sl < 8; ++sl) {
      s += red[sl * 128 + cc * 4 + hl];
      s2 += red[sl * 128 + cc * 4 + 2 + hl];
    }
    pbuf[blockIdx.x * 128 + ch] = s;
    pbuf[blockIdx.x * 128 + 64 + ch] = s2;
  }
}

// reduce pbuf -> stats[0:64]=a, stats[64:128]=b'
__global__ __launch_bounds__(256) void bnred(const float* __restrict__ pbuf,
                                             const float* __restrict__ g,
                                             const float* __restrict__ b, float invN,
                                             float* __restrict__ stats) {
  int tid = threadIdx.x;
  int ch = tid & 127;
  int q = tid >> 7;  // 0..1
  float s = 0.f;
  for (int r = q; r < NB_AGG; r += 2) s += pbuf[r * 128 + ch];
  __shared__ float red[256];
  red[tid] = s;
  __syncthreads();
  if (tid < 128) {
    float tot = red[tid] + red[128 + tid];
    red[tid] = tot;
  }
  __syncthreads();
  if (tid < 64) {
    float m = red[tid] * invN;
    float v = red[64 + tid] * invN - m * m;
    float a = g[tid] * rsqrtf(v + 1.0f);
    stats[tid] = a;
    stats[64 + tid] = b[tid] - m * a;
  }
}

// h fp32 -> bf16 activated features (BN + leaky)
__global__ void bnapply_kernel(const float* __restrict__ h, const float* __restrict__ stats,
                               unsigned short* __restrict__ xo, int N) {
  int gid = blockIdx.x * blockDim.x + threadIdx.x;
  if (gid >= N * 16) return;
  f32x4 v = ((const f32x4*)h)[gid];
  int c = (gid & 15) * 4;
  u16x4 o;
#pragma unroll
  for (int j = 0; j < 4; ++j) {
    float t = fmaf(stats[c + j], v[j], stats[64 + c + j]);
    o[j] = f2bf(fmaxf(t, 0.01f * t));
  }
  ((u16x4*)xo)[gid] = o;
}

// pure widening gather: out[row]=[xc[src]||xc[dst]] fp32.
// 16 threads/row, each reads u16x8 (8 channels) and writes two f32x4.
__global__ void gather_kernel(const unsigned short* __restrict__ xc,
                              const int* __restrict__ src0, const int* __restrict__ dst0,
                              const int* __restrict__ src1, const int* __restrict__ dst1,
                              float* __restrict__ out, int E) {
  int gid = blockIdx.x * blockDim.x + threadIdx.x;
  int total = 2 * E * 16;
  if (gid >= total) return;
  int row = gid >> 4, q = gid & 15;
  int e, s, d;
  if (row < E) {
    e = row; s = src0[e]; d = dst0[e];
  } else {
    e = row - E; s = src1[e]; d = dst1[e];
  }
  int node = (q < 8) ? s : d;
  int qq = q & 7;
  u16x8 v = *(const u16x8*)&xc[(size_t)node * 64 + qq * 8];
  f32x4 o0, o1;
#pragma unroll
  for (int j = 0; j < 4; ++j) {
    o0[j] = bfl((unsigned int)v[j]);
    o1[j] = bfl((unsigned int)v[4 + j]);
  }
  __builtin_nontemporal_store(o0, (f32x4*)out + gid * 2);
  __builtin_nontemporal_store(o1, (f32x4*)out + gid * 2 + 1);
}

extern "C" void kernel_launch(void* const* d_in, const int* in_sizes, int n_in,
                              void* d_out, int out_size, void* d_ws, size_t ws_size,
                              hipStream_t stream) {
  const float* x0 = (const float*)d_in[0];
  const int* ei0 = (const int*)d_in[1];
  const int* ei1 = (const int*)d_in[2];
  const float* bn1_g = (const float*)d_in[15];
  const float* bn1_b = (const float*)d_in[16];
  const float* bn2_g = (const float*)d_in[17];
  const float* bn2_b = (const float*)d_in[18];

  const int N = in_sizes[0] / 128;
  const int E = in_sizes[1] / 2;
  const int *src0 = ei0, *dst0 = ei0 + E;
  const int *src1 = ei1, *dst1 = ei1 + E;

  char* wsb = (char*)d_ws;
  size_t off = 0;
  auto alloc = [&](size_t bytes) {
    char* p = wsb + off;
    off = (off + bytes + 255) & ~(size_t)255;
    return (void*)p;
  };
  unsigned short* Wfb1 = (unsigned short*)alloc(192 * 128 * 2);
  unsigned short* Wfb2 = (unsigned short*)alloc(192 * 64 * 2);
  float* stats1 = (float*)alloc(128 * 4);
  float* stats2 = (float*)alloc(128 * 4);
  int* bsum = (int*)alloc(2 * NB_SCAN * 4);
  int* bbase = (int*)alloc(2 * NB_SCAN * 4);
  float* pbuf = (float*)alloc((size_t)NB_AGG * 128 * 4);
  int* cnt0 = (int*)alloc((size_t)N * 4);
  int* cnt1 = (int*)alloc((size_t)N * 4);
  int* base0 = (int*)alloc(((size_t)N + 1) * 4);
  int* base1 = (int*)alloc(((size_t)N + 1) * 4);
  int* csr0 = (int*)alloc((size_t)E * 4);
  int* csr1 = (int*)alloc((size_t)E * 4);
  unsigned short* xb = (unsigned short*)alloc((size_t)N * 128 * 2);
  float* h = (float*)alloc((size_t)N * 64 * 4);
  float* h2 = (float*)alloc((size_t)N * 64 * 4);
  unsigned short* P0 = (unsigned short*)alloc((size_t)N * 64 * 2);
  unsigned short* P1 = (unsigned short*)alloc((size_t)N * 64 * 2);
  unsigned short* xcb = (unsigned short*)alloc((size_t)N * 64 * 2);
  unsigned short* xc2 = (unsigned short*)alloc((size_t)N * 64 * 2);

  const float invN = 1.0f / (float)N;
  const int eg = (E + 255) / 256;
  const int chunk = (N + NB_SCAN - 1) / NB_SCAN;
  const int cvtB = (N * 32 + 255) / 256;

  zero_cnt<<<(N + 255) / 256, 256, 0, stream>>>(cnt0, cnt1, N);
  prep_kernel<<<cvtB + 96 + 48, 256, 0, stream>>>(
      x0, xb, N * 32, cvtB,
      (const float*)d_in[3], (const float*)d_in[4], (const float*)d_in[5],
      (const float*)d_in[6], (const float*)d_in[7], (const float*)d_in[8], Wfb1,
      (const float*)d_in[9], (const float*)d_in[10], (const float*)d_in[11],
      (const float*)d_in[12], (const float*)d_in[13], (const float*)d_in[14], Wfb2);
  count_both<<<2 * eg, 256, 0, stream>>>(dst0, dst1, cnt0, cnt1, E, eg);
  scanA<<<2 * NB_SCAN, 256, 0, stream>>>(cnt0, cnt1, bsum, N, chunk);
  scanB<<<1, 2 * NB_SCAN, 0, stream>>>(bsum, bbase);
  scanC<<<2 * NB_SCAN, 256, 0, stream>>>(cnt0, cnt1, bbase, base0, base1, N, chunk, E);
  fill_both<<<2 * eg, 256, 0, stream>>>(src0, dst0, base0, cnt0, csr0,
                                        src1, dst1, base1, cnt1, csr1, E, eg);

  const int mmGrid = (N + 63) / 64;

  // layer 1
  mm_mfma<128><<<mmGrid, 256, 0, stream>>>(xb, Wfb1, h, P0, P1, N);
  agg_kernel<<<NB_AGG, 256, 0, stream>>>(h, P0, P1, csr0, base0, csr1, base1, N, pbuf);
  bnred<<<1, 256, 0, stream>>>(pbuf, bn1_g, bn1_b, invN, stats1);
  bnapply_kernel<<<(N * 16 + 255) / 256, 256, 0, stream>>>(h, stats1, xcb, N);

  // layer 2
  mm_mfma<64><<<mmGrid, 256, 0, stream>>>(xcb, Wfb2, h2, P0, P1, N);
  agg_kernel<<<NB_AGG, 256, 0, stream>>>(h2, P0, P1, csr0, base0, csr1, base1, N, pbuf);
  bnred<<<1, 256, 0, stream>>>(pbuf, bn2_g, bn2_b, invN, stats2);
  bnapply_kernel<<<(N * 16 + 255) / 256, 256, 0, stream>>>(h2, stats2, xc2, N);

  // output gather (pure widen-copy)
  gather_kernel<<<(2 * E * 16 + 255) / 256, 256, 0, stream>>>(
      xc2, src0, dst0, src1, dst1, (float*)d_out, E);
}

// Round 6
// 367.558 us; speedup vs baseline: 1.9195x; 1.9195x over previous
//
#include <hip/hip_runtime.h>
#include <math.h>

// ---------------------------------------------------------------------------
// HeteroGNN forward. bf16 MFMA GEMM (B-in-registers, A from global, no LDS),
// bf16 projected features, CSR mean-agg (simple unrollable loop, one
// half-wave per node), hierarchical scan, round-3 BN chain, bf16 final
// features, dense-coalesced widening gather.
//   Wf (192 x F) = [ 0.5*(Wul0@Wd0 + Wul1@Wd1) ; 0.5*Wur0@Ws0 ; 0.5*Wur1@Ws1 ]
//   [h | P0 | P1] = x @ Wf^T   (h fp32, P bf16)
//   h[d] += mean_{csr0[d]} P0[src] + mean_{csr1[d]} P1[src]
//   BN(train, eps=1, biased) + LeakyReLU(0.01) -> bf16
// ---------------------------------------------------------------------------

typedef float f32x4 __attribute__((ext_vector_type(4)));
typedef float f32x2 __attribute__((ext_vector_type(2)));
typedef short bf16x8 __attribute__((ext_vector_type(8)));
typedef unsigned short u16x4 __attribute__((ext_vector_type(4)));

#define NB_SCAN 64  // scan blocks per edge type

static __device__ __forceinline__ unsigned short f2bf(float f) {
  unsigned int u = __builtin_bit_cast(unsigned int, f);
  unsigned int r = (u + 0x7FFFu + ((u >> 16) & 1u)) >> 16;
  return (unsigned short)r;
}
static __device__ __forceinline__ float bfl(unsigned int u) {
  return __builtin_bit_cast(float, u << 16);
}
static __device__ __forceinline__ float bfh(unsigned int u) {
  return __builtin_bit_cast(float, u & 0xFFFF0000u);
}

__global__ void zero_cnt(int* __restrict__ cnt0, int* __restrict__ cnt1,
                         float* __restrict__ s1, float* __restrict__ s2, int N) {
  int g = blockIdx.x * 256 + threadIdx.x;
  if (g < N) { cnt0[g] = 0; cnt1[g] = 0; }
  if (g < 256) { s1[g] = 0.f; s2[g] = 0.f; }
}

// cvt x->bf16 (blocks [0, cvtB)), fusew1 (next 96), fusew2 (next 48)
__global__ void prep_kernel(const float* __restrict__ x, unsigned short* __restrict__ xb,
                            int n4, int cvtB,
                            const float* __restrict__ Wd10, const float* __restrict__ Ws10,
                            const float* __restrict__ Wu10, const float* __restrict__ Wd11,
                            const float* __restrict__ Ws11, const float* __restrict__ Wu11,
                            unsigned short* __restrict__ Wfb1,
                            const float* __restrict__ Wd20, const float* __restrict__ Ws20,
                            const float* __restrict__ Wu20, const float* __restrict__ Wd21,
                            const float* __restrict__ Ws21, const float* __restrict__ Wu21,
                            unsigned short* __restrict__ Wfb2) {
  int b = blockIdx.x;
  if (b < cvtB) {
    int g = b * 256 + threadIdx.x;
    if (g >= n4) return;
    f32x4 v = ((const f32x4*)x)[g];
    u16x4 o;
#pragma unroll
    for (int j = 0; j < 4; ++j) o[j] = f2bf(v[j]);
    ((u16x4*)xb)[g] = o;
    return;
  }
  const float *Wd0, *Ws0, *Wu0, *Wd1, *Ws1, *Wu1;
  unsigned short* Wfb;
  int K, gid;
  if (b < cvtB + 96) {
    Wd0 = Wd10; Ws0 = Ws10; Wu0 = Wu10; Wd1 = Wd11; Ws1 = Ws11; Wu1 = Wu11;
    Wfb = Wfb1; K = 128;
    gid = (b - cvtB) * 256 + threadIdx.x;
  } else {
    Wd0 = Wd20; Ws0 = Ws20; Wu0 = Wu20; Wd1 = Wd21; Ws1 = Ws21; Wu1 = Wu21;
    Wfb = Wfb2; K = 64;
    gid = (b - cvtB - 96) * 256 + threadIdx.x;
  }
  if (gid >= 192 * K) return;
  int i = gid / K, j = gid - i * K;
  float s = 0.f;
  if (i < 64) {
#pragma unroll 4
    for (int k = 0; k < 64; ++k)
      s += Wu0[i * 128 + k] * Wd0[k * K + j] + Wu1[i * 128 + k] * Wd1[k * K + j];
  } else if (i < 128) {
    int ii = i - 64;
#pragma unroll 4
    for (int k = 0; k < 64; ++k) s += Wu0[ii * 128 + 64 + k] * Ws0[k * K + j];
  } else {
    int ii = i - 128;
#pragma unroll 4
    for (int k = 0; k < 64; ++k) s += Wu1[ii * 128 + 64 + k] * Ws1[k * K + j];
  }
  Wfb[gid] = f2bf(0.5f * s);
}

__global__ void count_both(const int* __restrict__ dst0, const int* __restrict__ dst1,
                           int* __restrict__ cnt0, int* __restrict__ cnt1, int E, int eg) {
  int b = blockIdx.x;
  bool t1 = b >= eg;
  int e = (t1 ? b - eg : b) * 256 + threadIdx.x;
  if (e >= E) return;
  if (t1) atomicAdd(&cnt1[dst1[e]], 1);
  else atomicAdd(&cnt0[dst0[e]], 1);
}

// scan stage A: per-block sums. 2*NB_SCAN blocks.
__global__ __launch_bounds__(256) void scanA(const int* __restrict__ cnt0,
                                             const int* __restrict__ cnt1,
                                             int* __restrict__ bsum, int N, int chunk) {
  int b = blockIdx.x;
  const int* cnt = (b < NB_SCAN) ? cnt0 : cnt1;
  int lb = (b < NB_SCAN) ? b : b - NB_SCAN;
  int lo = lb * chunk, hi = min(lo + chunk, N);
  int s = 0;
  for (int i = lo + threadIdx.x; i < hi; i += 256) s += cnt[i];
  __shared__ int red[256];
  red[threadIdx.x] = s;
  __syncthreads();
  for (int off = 128; off > 0; off >>= 1) {
    if (threadIdx.x < off) red[threadIdx.x] += red[threadIdx.x + off];
    __syncthreads();
  }
  if (threadIdx.x == 0) bsum[b] = red[0];
}

// scan stage B: exclusive scan of bsum per type. 1 block, 128 threads.
__global__ void scanB(const int* __restrict__ bsum, int* __restrict__ bbase) {
  __shared__ int l[2 * NB_SCAN];
  int t = threadIdx.x;
  int v0 = bsum[t];
  l[t] = v0;
  __syncthreads();
  for (int off = 1; off < NB_SCAN; off <<= 1) {
    int v = l[t];
    if ((t & (NB_SCAN - 1)) >= off) v += l[t - off];
    __syncthreads();
    l[t] = v;
    __syncthreads();
  }
  bbase[t] = l[t] - v0;
}

// scan stage C: per-block local exclusive scan + write base. 2*NB_SCAN blocks.
__global__ __launch_bounds__(256) void scanC(const int* __restrict__ cnt0,
                                             const int* __restrict__ cnt1,
                                             const int* __restrict__ bbase,
                                             int* __restrict__ base0, int* __restrict__ base1,
                                             int N, int chunk, int E) {
  int b = blockIdx.x;
  const int* cnt = (b < NB_SCAN) ? cnt0 : cnt1;
  int* base = (b < NB_SCAN) ? base0 : base1;
  int lb = (b < NB_SCAN) ? b : b - NB_SCAN;
  int lo = lb * chunk, hi = min(lo + chunk, N);
  int t = threadIdx.x;
  int v[4];
  int ls = 0;
  int i0 = lo + t * 4;
#pragma unroll
  for (int j = 0; j < 4; ++j) {
    v[j] = (i0 + j < hi) ? cnt[i0 + j] : 0;
    ls += v[j];
  }
  __shared__ int l[256];
  l[t] = ls;
  __syncthreads();
  for (int off = 1; off < 256; off <<= 1) {
    int x = l[t];
    if (t >= off) x += l[t - off];
    __syncthreads();
    l[t] = x;
    __syncthreads();
  }
  int run = bbase[b] + l[t] - ls;
#pragma unroll
  for (int j = 0; j < 4; ++j) {
    if (i0 + j < hi) base[i0 + j] = run;
    run += v[j];
  }
  if (t == 0 && lb == NB_SCAN - 1) base[N] = E;
}

__global__ void fill_both(const int* __restrict__ src0, const int* __restrict__ dst0,
                          const int* __restrict__ base0, int* __restrict__ cnt0,
                          int* __restrict__ csr0,
                          const int* __restrict__ src1, const int* __restrict__ dst1,
                          const int* __restrict__ base1, int* __restrict__ cnt1,
                          int* __restrict__ csr1, int E, int eg) {
  int b = blockIdx.x;
  bool t1 = b >= eg;
  int e = (t1 ? b - eg : b) * 256 + threadIdx.x;
  if (e >= E) return;
  const int* src = t1 ? src1 : src0;
  const int* dst = t1 ? dst1 : dst0;
  const int* base = t1 ? base1 : base0;
  int* cnt = t1 ? cnt1 : cnt0;
  int* csr = t1 ? csr1 : csr0;
  int d = dst[e];
  int p = atomicSub(&cnt[d], 1) - 1;
  csr[base[d] + p] = src[e];
}

// [h|P0|P1] = xb[N,K](bf16) @ Wfb[192,K]^T(bf16). 64 rows/block, 4 waves x 48 cols.
template <int K>
__global__ __launch_bounds__(256) void mm_mfma(const unsigned short* __restrict__ xb,
                                               const unsigned short* __restrict__ Wfb,
                                               float* __restrict__ h,
                                               unsigned short* __restrict__ P0,
                                               unsigned short* __restrict__ P1, int N) {
  constexpr int NKS = K / 32;
  int tid = threadIdx.x;
  int l = tid & 63;
  int wv = tid >> 6;
  int lr = l & 15;
  int lj = l >> 4;
  int brow = blockIdx.x * 64;
  int wcol = wv * 48;

  bf16x8 B[3 * NKS];
#pragma unroll
  for (int ct = 0; ct < 3; ++ct)
#pragma unroll
    for (int ks = 0; ks < NKS; ++ks) {
      int col = wcol + ct * 16 + lr;
      B[ct * NKS + ks] = *(const bf16x8*)&Wfb[(size_t)col * K + ks * 32 + lj * 8];
    }

  f32x4 acc[4][3];
#pragma unroll
  for (int rt = 0; rt < 4; ++rt)
#pragma unroll
    for (int ct = 0; ct < 3; ++ct) acc[rt][ct] = (f32x4){0.f, 0.f, 0.f, 0.f};

#pragma unroll
  for (int ks = 0; ks < NKS; ++ks) {
    bf16x8 A[4];
#pragma unroll
    for (int rt = 0; rt < 4; ++rt) {
      int row = brow + rt * 16 + lr;
      if (row >= N) row = N - 1;
      A[rt] = *(const bf16x8*)&xb[(size_t)row * K + ks * 32 + lj * 8];
    }
#pragma unroll
    for (int rt = 0; rt < 4; ++rt)
#pragma unroll
      for (int ct = 0; ct < 3; ++ct)
        acc[rt][ct] =
            __builtin_amdgcn_mfma_f32_16x16x32_bf16(A[rt], B[ct * NKS + ks], acc[rt][ct], 0, 0, 0);
  }

#pragma unroll
  for (int rt = 0; rt < 4; ++rt)
#pragma unroll
    for (int ct = 0; ct < 3; ++ct) {
      int gct = (wcol >> 4) + ct;
      int sel = gct >> 2;
      int c0 = (gct & 3) * 16 + lr;
#pragma unroll
      for (int r = 0; r < 4; ++r) {
        int row = brow + rt * 16 + lj * 4 + r;
        if (row < N) {
          if (sel == 0) h[(size_t)row * 64 + c0] = acc[rt][ct][r];
          else if (sel == 1) P0[(size_t)row * 64 + c0] = f2bf(acc[rt][ct][r]);
          else P1[(size_t)row * 64 + c0] = f2bf(acc[rt][ct][r]);
        }
      }
    }
}

// half-wave (32 lanes, 2 ch/lane) per dst node; simple loop -> compiler
// unrolls and keeps multiple gathers in flight. bf16 reads, fp32 accumulate.
__global__ void agg_kernel(float* __restrict__ h, const unsigned short* __restrict__ P0,
                           const unsigned short* __restrict__ P1,
                           const int* __restrict__ csr0, const int* __restrict__ base0,
                           const int* __restrict__ csr1, const int* __restrict__ base1,
                           int N) {
  int gid = blockIdx.x * blockDim.x + threadIdx.x;
  int w = gid >> 5, c = gid & 31;
  if (w >= N) return;
  int co = 2 * c;
  float a0 = 0.f, a1 = 0.f;
  int b0 = base0[w], e0 = base0[w + 1];
  for (int i = b0; i < e0; ++i) {
    unsigned int u = *(const unsigned int*)&P0[(size_t)csr0[i] * 64 + co];
    a0 += bfl(u);
    a1 += bfh(u);
  }
  float i0 = 1.0f / fmaxf((float)(e0 - b0), 1.0f);
  float s0 = a0 * i0, s1 = a1 * i0;
  a0 = 0.f; a1 = 0.f;
  int b1 = base1[w], e1 = base1[w + 1];
  for (int i = b1; i < e1; ++i) {
    unsigned int u = *(const unsigned int*)&P1[(size_t)csr1[i] * 64 + co];
    a0 += bfl(u);
    a1 += bfh(u);
  }
  float i1 = 1.0f / fmaxf((float)(e1 - b1), 1.0f);
  s0 += a0 * i1;
  s1 += a1 * i1;
  f32x2* hp = (f32x2*)&h[(size_t)w * 64 + co];
  f32x2 hv = *hp;
  hv.x += s0;
  hv.y += s1;
  *hp = hv;
}

__global__ __launch_bounds__(256) void bnstats_kernel(const float* __restrict__ h,
                                                      float* __restrict__ stats, int N) {
  int tid = threadIdx.x;
  int c = tid & 63;
  int part = tid >> 6;
  float s = 0.f, s2 = 0.f;
  for (int r = blockIdx.x * 4 + part; r < N; r += gridDim.x * 4) {
    float v = h[(size_t)r * 64 + c];
    s += v;
    s2 += v * v;
  }
  __shared__ float red[512];
  red[tid] = s;
  red[256 + tid] = s2;
  __syncthreads();
  if (part == 0) {
    s = red[c] + red[64 + c] + red[128 + c] + red[192 + c];
    s2 = red[256 + c] + red[256 + 64 + c] + red[256 + 128 + c] + red[256 + 192 + c];
    atomicAdd(&stats[c], s);
    atomicAdd(&stats[64 + c], s2);
  }
}

// stats[0:64]=sum, [64:128]=sumsq -> [128:192]=a, [192:256]=b'
__global__ void bnfinal_kernel(float* __restrict__ stats, const float* __restrict__ g,
                               const float* __restrict__ b, float invN) {
  int c = threadIdx.x;
  if (c >= 64) return;
  float m = stats[c] * invN;
  float v = stats[64 + c] * invN - m * m;
  float a = g[c] * rsqrtf(v + 1.0f);
  stats[128 + c] = a;
  stats[192 + c] = b[c] - m * a;
}

// h fp32 -> bf16 activated features (BN + leaky)
__global__ void bnapply_kernel(const float* __restrict__ h, const float* __restrict__ stats,
                               unsigned short* __restrict__ xo, int N) {
  int gid = blockIdx.x * blockDim.x + threadIdx.x;
  if (gid >= N * 16) return;
  f32x4 v = ((const f32x4*)h)[gid];
  int c = (gid & 15) * 4;
  const float* a = stats + 128;
  const float* bb = stats + 192;
  u16x4 o;
#pragma unroll
  for (int j = 0; j < 4; ++j) {
    float t = fmaf(a[c + j], v[j], bb[c + j]);
    o[j] = f2bf(fmaxf(t, 0.01f * t));
  }
  ((u16x4*)xo)[gid] = o;
}

// widening gather: out[row]=[xc[src]||xc[dst]] fp32; 32 threads/row,
// each reads u16x4 (8B) and writes ONE dense f32x4 (16B) -> fully coalesced.
__global__ void gather_kernel(const unsigned short* __restrict__ xc,
                              const int* __restrict__ src0, const int* __restrict__ dst0,
                              const int* __restrict__ src1, const int* __restrict__ dst1,
                              float* __restrict__ out, int E) {
  int gid = blockIdx.x * blockDim.x + threadIdx.x;
  int total = 2 * E * 32;
  if (gid >= total) return;
  int row = gid >> 5, q = gid & 31;
  int e, s, d;
  if (row < E) {
    e = row; s = src0[e]; d = dst0[e];
  } else {
    e = row - E; s = src1[e]; d = dst1[e];
  }
  int node = (q < 16) ? s : d;
  int qq = q & 15;
  u16x4 v = *(const u16x4*)&xc[(size_t)node * 64 + qq * 4];
  f32x4 o;
#pragma unroll
  for (int j = 0; j < 4; ++j) o[j] = bfl((unsigned int)v[j]);
  __builtin_nontemporal_store(o, (f32x4*)out + gid);
}

extern "C" void kernel_launch(void* const* d_in, const int* in_sizes, int n_in,
                              void* d_out, int out_size, void* d_ws, size_t ws_size,
                              hipStream_t stream) {
  const float* x0 = (const float*)d_in[0];
  const int* ei0 = (const int*)d_in[1];
  const int* ei1 = (const int*)d_in[2];
  const float* bn1_g = (const float*)d_in[15];
  const float* bn1_b = (const float*)d_in[16];
  const float* bn2_g = (const float*)d_in[17];
  const float* bn2_b = (const float*)d_in[18];

  const int N = in_sizes[0] / 128;
  const int E = in_sizes[1] / 2;
  const int *src0 = ei0, *dst0 = ei0 + E;
  const int *src1 = ei1, *dst1 = ei1 + E;

  char* wsb = (char*)d_ws;
  size_t off = 0;
  auto alloc = [&](size_t bytes) {
    char* p = wsb + off;
    off = (off + bytes + 255) & ~(size_t)255;
    return (void*)p;
  };
  unsigned short* Wfb1 = (unsigned short*)alloc(192 * 128 * 2);
  unsigned short* Wfb2 = (unsigned short*)alloc(192 * 64 * 2);
  float* stats1 = (float*)alloc(256 * 4);
  float* stats2 = (float*)alloc(256 * 4);
  int* bsum = (int*)alloc(2 * NB_SCAN * 4);
  int* bbase = (int*)alloc(2 * NB_SCAN * 4);
  int* cnt0 = (int*)alloc((size_t)N * 4);
  int* cnt1 = (int*)alloc((size_t)N * 4);
  int* base0 = (int*)alloc(((size_t)N + 1) * 4);
  int* base1 = (int*)alloc(((size_t)N + 1) * 4);
  int* csr0 = (int*)alloc((size_t)E * 4);
  int* csr1 = (int*)alloc((size_t)E * 4);
  unsigned short* xb = (unsigned short*)alloc((size_t)N * 128 * 2);
  float* h = (float*)alloc((size_t)N * 64 * 4);
  float* h2 = (float*)alloc((size_t)N * 64 * 4);
  unsigned short* P0 = (unsigned short*)alloc((size_t)N * 64 * 2);
  unsigned short* P1 = (unsigned short*)alloc((size_t)N * 64 * 2);
  unsigned short* xcb = (unsigned short*)alloc((size_t)N * 64 * 2);
  unsigned short* xc2 = (unsigned short*)alloc((size_t)N * 64 * 2);

  const float invN = 1.0f / (float)N;
  const int eg = (E + 255) / 256;
  const int chunk = (N + NB_SCAN - 1) / NB_SCAN;
  const int cvtB = (N * 32 + 255) / 256;

  zero_cnt<<<(N + 255) / 256, 256, 0, stream>>>(cnt0, cnt1, stats1, stats2, N);
  prep_kernel<<<cvtB + 96 + 48, 256, 0, stream>>>(
      x0, xb, N * 32, cvtB,
      (const float*)d_in[3], (const float*)d_in[4], (const float*)d_in[5],
      (const float*)d_in[6], (const float*)d_in[7], (const float*)d_in[8], Wfb1,
      (const float*)d_in[9], (const float*)d_in[10], (const float*)d_in[11],
      (const float*)d_in[12], (const float*)d_in[13], (const float*)d_in[14], Wfb2);
  count_both<<<2 * eg, 256, 0, stream>>>(dst0, dst1, cnt0, cnt1, E, eg);
  scanA<<<2 * NB_SCAN, 256, 0, stream>>>(cnt0, cnt1, bsum, N, chunk);
  scanB<<<1, 2 * NB_SCAN, 0, stream>>>(bsum, bbase);
  scanC<<<2 * NB_SCAN, 256, 0, stream>>>(cnt0, cnt1, bbase, base0, base1, N, chunk, E);
  fill_both<<<2 * eg, 256, 0, stream>>>(src0, dst0, base0, cnt0, csr0,
                                        src1, dst1, base1, cnt1, csr1, E, eg);

  const int mmGrid = (N + 63) / 64;
  const int aggGrid = (N * 32 + 255) / 256;

  // layer 1
  mm_mfma<128><<<mmGrid, 256, 0, stream>>>(xb, Wfb1, h, P0, P1, N);
  agg_kernel<<<aggGrid, 256, 0, stream>>>(h, P0, P1, csr0, base0, csr1, base1, N);
  bnstats_kernel<<<256, 256, 0, stream>>>(h, stats1, N);
  bnfinal_kernel<<<1, 64, 0, stream>>>(stats1, bn1_g, bn1_b, invN);
  bnapply_kernel<<<(N * 16 + 255) / 256, 256, 0, stream>>>(h, stats1, xcb, N);

  // layer 2
  mm_mfma<64><<<mmGrid, 256, 0, stream>>>(xcb, Wfb2, h2, P0, P1, N);
  agg_kernel<<<aggGrid, 256, 0, stream>>>(h2, P0, P1, csr0, base0, csr1, base1, N);
  bnstats_kernel<<<256, 256, 0, stream>>>(h2, stats2, N);
  bnfinal_kernel<<<1, 64, 0, stream>>>(stats2, bn2_g, bn2_b, invN);
  bnapply_kernel<<<(N * 16 + 255) / 256, 256, 0, stream>>>(h2, stats2, xc2, N);

  // output gather (dense coalesced widen-copy)
  gather_kernel<<<(2 * E * 32 + 255) / 256, 256, 0, stream>>>(
      xc2, src0, dst0, src1, dst1, (float*)d_out, E);
}

// Round 7
// 365.471 us; speedup vs baseline: 1.9305x; 1.0057x over previous
//
#include <hip/hip_runtime.h>
#include <math.h>

// ---------------------------------------------------------------------------
// HeteroGNN forward. bf16 MFMA GEMM with fp32 A-load + inline cvt (mm1) and
// inline BN+LeakyReLU (mm2); bf16 projected features; CSR mean-agg (simple
// unrollable loop, half-wave per node); hierarchical scan; BN stats via
// 256-block atomics; a/b derived in-block by consumers; dense widening gather.
//   Wf (192 x F) = [ 0.5*(Wul0@Wd0 + Wul1@Wd1) ; 0.5*Wur0@Ws0 ; 0.5*Wur1@Ws1 ]
//   [h | P0 | P1] = x @ Wf^T   (h fp32, P bf16)
//   h[d] += mean_{csr0[d]} P0[src] + mean_{csr1[d]} P1[src]
//   BN(train, eps=1, biased) + LeakyReLU(0.01)
// ---------------------------------------------------------------------------

typedef float f32x4 __attribute__((ext_vector_type(4)));
typedef float f32x2 __attribute__((ext_vector_type(2)));
typedef short bf16x8 __attribute__((ext_vector_type(8)));
typedef unsigned short u16x4 __attribute__((ext_vector_type(4)));

#define NB_SCAN 64  // scan blocks per edge type

static __device__ __forceinline__ unsigned short f2bf(float f) {
  unsigned int u = __builtin_bit_cast(unsigned int, f);
  unsigned int r = (u + 0x7FFFu + ((u >> 16) & 1u)) >> 16;
  return (unsigned short)r;
}
static __device__ __forceinline__ float bfl(unsigned int u) {
  return __builtin_bit_cast(float, u << 16);
}
static __device__ __forceinline__ float bfh(unsigned int u) {
  return __builtin_bit_cast(float, u & 0xFFFF0000u);
}

// fusew1 (blocks [0,96)), fusew2 ([96,144)), zero cnt+stats ([144, 144+zb))
__global__ void prep_kernel(const float* __restrict__ Wd10, const float* __restrict__ Ws10,
                            const float* __restrict__ Wu10, const float* __restrict__ Wd11,
                            const float* __restrict__ Ws11, const float* __restrict__ Wu11,
                            unsigned short* __restrict__ Wfb1,
                            const float* __restrict__ Wd20, const float* __restrict__ Ws20,
                            const float* __restrict__ Wu20, const float* __restrict__ Wd21,
                            const float* __restrict__ Ws21, const float* __restrict__ Wu21,
                            unsigned short* __restrict__ Wfb2,
                            int* __restrict__ cnt0, int* __restrict__ cnt1,
                            float* __restrict__ s1, float* __restrict__ s2, int N) {
  int b = blockIdx.x;
  if (b >= 144) {
    int g = (b - 144) * 256 + threadIdx.x;
    if (g < N) { cnt0[g] = 0; cnt1[g] = 0; }
    if (g < 128) { s1[g] = 0.f; s2[g] = 0.f; }
    return;
  }
  const float *Wd0, *Ws0, *Wu0, *Wd1, *Ws1, *Wu1;
  unsigned short* Wfb;
  int K, gid;
  if (b < 96) {
    Wd0 = Wd10; Ws0 = Ws10; Wu0 = Wu10; Wd1 = Wd11; Ws1 = Ws11; Wu1 = Wu11;
    Wfb = Wfb1; K = 128;
    gid = b * 256 + threadIdx.x;
  } else {
    Wd0 = Wd20; Ws0 = Ws20; Wu0 = Wu20; Wd1 = Wd21; Ws1 = Ws21; Wu1 = Wu21;
    Wfb = Wfb2; K = 64;
    gid = (b - 96) * 256 + threadIdx.x;
  }
  if (gid >= 192 * K) return;
  int i = gid / K, j = gid - i * K;
  float s = 0.f;
  if (i < 64) {
#pragma unroll 4
    for (int k = 0; k < 64; ++k)
      s += Wu0[i * 128 + k] * Wd0[k * K + j] + Wu1[i * 128 + k] * Wd1[k * K + j];
  } else if (i < 128) {
    int ii = i - 64;
#pragma unroll 4
    for (int k = 0; k < 64; ++k) s += Wu0[ii * 128 + 64 + k] * Ws0[k * K + j];
  } else {
    int ii = i - 128;
#pragma unroll 4
    for (int k = 0; k < 64; ++k) s += Wu1[ii * 128 + 64 + k] * Ws1[k * K + j];
  }
  Wfb[gid] = f2bf(0.5f * s);
}

__global__ void count_both(const int* __restrict__ dst0, const int* __restrict__ dst1,
                           int* __restrict__ cnt0, int* __restrict__ cnt1, int E, int eg) {
  int b = blockIdx.x;
  bool t1 = b >= eg;
  int e = (t1 ? b - eg : b) * 256 + threadIdx.x;
  if (e >= E) return;
  if (t1) atomicAdd(&cnt1[dst1[e]], 1);
  else atomicAdd(&cnt0[dst0[e]], 1);
}

// scan stage A: per-block sums. 2*NB_SCAN blocks.
__global__ __launch_bounds__(256) void scanA(const int* __restrict__ cnt0,
                                             const int* __restrict__ cnt1,
                                             int* __restrict__ bsum, int N, int chunk) {
  int b = blockIdx.x;
  const int* cnt = (b < NB_SCAN) ? cnt0 : cnt1;
  int lb = (b < NB_SCAN) ? b : b - NB_SCAN;
  int lo = lb * chunk, hi = min(lo + chunk, N);
  int s = 0;
  for (int i = lo + threadIdx.x; i < hi; i += 256) s += cnt[i];
  __shared__ int red[256];
  red[threadIdx.x] = s;
  __syncthreads();
  for (int off = 128; off > 0; off >>= 1) {
    if (threadIdx.x < off) red[threadIdx.x] += red[threadIdx.x + off];
    __syncthreads();
  }
  if (threadIdx.x == 0) bsum[b] = red[0];
}

// scan stage B: exclusive scan of bsum per type. 1 block, 128 threads.
__global__ void scanB(const int* __restrict__ bsum, int* __restrict__ bbase) {
  __shared__ int l[2 * NB_SCAN];
  int t = threadIdx.x;
  int v0 = bsum[t];
  l[t] = v0;
  __syncthreads();
  for (int off = 1; off < NB_SCAN; off <<= 1) {
    int v = l[t];
    if ((t & (NB_SCAN - 1)) >= off) v += l[t - off];
    __syncthreads();
    l[t] = v;
    __syncthreads();
  }
  bbase[t] = l[t] - v0;
}

// scan stage C: per-block local exclusive scan + write base. 2*NB_SCAN blocks.
__global__ __launch_bounds__(256) void scanC(const int* __restrict__ cnt0,
                                             const int* __restrict__ cnt1,
                                             const int* __restrict__ bbase,
                                             int* __restrict__ base0, int* __restrict__ base1,
                                             int N, int chunk, int E) {
  int b = blockIdx.x;
  const int* cnt = (b < NB_SCAN) ? cnt0 : cnt1;
  int* base = (b < NB_SCAN) ? base0 : base1;
  int lb = (b < NB_SCAN) ? b : b - NB_SCAN;
  int lo = lb * chunk, hi = min(lo + chunk, N);
  int t = threadIdx.x;
  int v[4];
  int ls = 0;
  int i0 = lo + t * 4;
#pragma unroll
  for (int j = 0; j < 4; ++j) {
    v[j] = (i0 + j < hi) ? cnt[i0 + j] : 0;
    ls += v[j];
  }
  __shared__ int l[256];
  l[t] = ls;
  __syncthreads();
  for (int off = 1; off < 256; off <<= 1) {
    int x = l[t];
    if (t >= off) x += l[t - off];
    __syncthreads();
    l[t] = x;
    __syncthreads();
  }
  int run = bbase[b] + l[t] - ls;
#pragma unroll
  for (int j = 0; j < 4; ++j) {
    if (i0 + j < hi) base[i0 + j] = run;
    run += v[j];
  }
  if (t == 0 && lb == NB_SCAN - 1) base[N] = E;
}

__global__ void fill_both(const int* __restrict__ src0, const int* __restrict__ dst0,
                          const int* __restrict__ base0, int* __restrict__ cnt0,
                          int* __restrict__ csr0,
                          const int* __restrict__ src1, const int* __restrict__ dst1,
                          const int* __restrict__ base1, int* __restrict__ cnt1,
                          int* __restrict__ csr1, int E, int eg) {
  int b = blockIdx.x;
  bool t1 = b >= eg;
  int e = (t1 ? b - eg : b) * 256 + threadIdx.x;
  if (e >= E) return;
  const int* src = t1 ? src1 : src0;
  const int* dst = t1 ? dst1 : dst0;
  const int* base = t1 ? base1 : base0;
  int* cnt = t1 ? cnt1 : cnt0;
  int* csr = t1 ? csr1 : csr0;
  int d = dst[e];
  int p = atomicSub(&cnt[d], 1) - 1;
  csr[base[d] + p] = src[e];
}

// [h|P0|P1] = f(xa)[N,K] @ Wfb[192,K]^T.  A is fp32; BN=false: plain cvt,
// BN=true: y = a*x+b', leaky(0.01) (a,b' derived in-block from raw sums).
// 64 rows/block, 4 waves x 48 cols.
template <int K, bool BN>
__global__ __launch_bounds__(256) void mm_mfma(const float* __restrict__ xa,
                                               const unsigned short* __restrict__ Wfb,
                                               const float* __restrict__ stats,
                                               const float* __restrict__ gg,
                                               const float* __restrict__ bb, float invN,
                                               float* __restrict__ h,
                                               unsigned short* __restrict__ P0,
                                               unsigned short* __restrict__ P1, int N) {
  constexpr int NKS = K / 32;
  __shared__ float sa[64], sb[64];
  int tid = threadIdx.x;
  if constexpr (BN) {
    if (tid < 64) {
      float m = stats[tid] * invN;
      float v = stats[64 + tid] * invN - m * m;
      float a = gg[tid] * rsqrtf(v + 1.0f);
      sa[tid] = a;
      sb[tid] = bb[tid] - m * a;
    }
    __syncthreads();
  }
  int l = tid & 63;
  int wv = tid >> 6;
  int lr = l & 15;
  int lj = l >> 4;
  int brow = blockIdx.x * 64;
  int wcol = wv * 48;

  bf16x8 B[3 * NKS];
#pragma unroll
  for (int ct = 0; ct < 3; ++ct)
#pragma unroll
    for (int ks = 0; ks < NKS; ++ks) {
      int col = wcol + ct * 16 + lr;
      B[ct * NKS + ks] = *(const bf16x8*)&Wfb[(size_t)col * K + ks * 32 + lj * 8];
    }

  f32x4 acc[4][3];
#pragma unroll
  for (int rt = 0; rt < 4; ++rt)
#pragma unroll
    for (int ct = 0; ct < 3; ++ct) acc[rt][ct] = (f32x4){0.f, 0.f, 0.f, 0.f};

#pragma unroll
  for (int ks = 0; ks < NKS; ++ks) {
    int colbase = ks * 32 + lj * 8;
    bf16x8 A[4];
#pragma unroll
    for (int rt = 0; rt < 4; ++rt) {
      int row = brow + rt * 16 + lr;
      if (row >= N) row = N - 1;
      const float* p = &xa[(size_t)row * K + colbase];
      f32x4 v0 = *(const f32x4*)p;
      f32x4 v1 = *(const f32x4*)(p + 4);
      bf16x8 r;
#pragma unroll
      for (int j = 0; j < 4; ++j) {
        float t0 = v0[j], t1 = v1[j];
        if constexpr (BN) {
          int c0 = colbase + j, c1 = colbase + 4 + j;
          t0 = fmaf(sa[c0], t0, sb[c0]);
          t0 = fmaxf(t0, 0.01f * t0);
          t1 = fmaf(sa[c1], t1, sb[c1]);
          t1 = fmaxf(t1, 0.01f * t1);
        }
        r[j] = (short)f2bf(t0);
        r[4 + j] = (short)f2bf(t1);
      }
      A[rt] = r;
    }
#pragma unroll
    for (int rt = 0; rt < 4; ++rt)
#pragma unroll
      for (int ct = 0; ct < 3; ++ct)
        acc[rt][ct] =
            __builtin_amdgcn_mfma_f32_16x16x32_bf16(A[rt], B[ct * NKS + ks], acc[rt][ct], 0, 0, 0);
  }

#pragma unroll
  for (int rt = 0; rt < 4; ++rt)
#pragma unroll
    for (int ct = 0; ct < 3; ++ct) {
      int gct = (wcol >> 4) + ct;
      int sel = gct >> 2;
      int c0 = (gct & 3) * 16 + lr;
#pragma unroll
      for (int r = 0; r < 4; ++r) {
        int row = brow + rt * 16 + lj * 4 + r;
        if (row < N) {
          if (sel == 0) h[(size_t)row * 64 + c0] = acc[rt][ct][r];
          else if (sel == 1) P0[(size_t)row * 64 + c0] = f2bf(acc[rt][ct][r]);
          else P1[(size_t)row * 64 + c0] = f2bf(acc[rt][ct][r]);
        }
      }
    }
}

// half-wave (32 lanes, 2 ch/lane) per dst node; simple loop -> compiler
// unrolls and keeps multiple gathers in flight. bf16 reads, fp32 accumulate.
__global__ void agg_kernel(float* __restrict__ h, const unsigned short* __restrict__ P0,
                           const unsigned short* __restrict__ P1,
                           const int* __restrict__ csr0, const int* __restrict__ base0,
                           const int* __restrict__ csr1, const int* __restrict__ base1,
                           int N) {
  int gid = blockIdx.x * blockDim.x + threadIdx.x;
  int w = gid >> 5, c = gid & 31;
  if (w >= N) return;
  int co = 2 * c;
  float a0 = 0.f, a1 = 0.f;
  int b0 = base0[w], e0 = base0[w + 1];
  for (int i = b0; i < e0; ++i) {
    unsigned int u = *(const unsigned int*)&P0[(size_t)csr0[i] * 64 + co];
    a0 += bfl(u);
    a1 += bfh(u);
  }
  float i0 = 1.0f / fmaxf((float)(e0 - b0), 1.0f);
  float s0 = a0 * i0, s1 = a1 * i0;
  a0 = 0.f; a1 = 0.f;
  int b1 = base1[w], e1 = base1[w + 1];
  for (int i = b1; i < e1; ++i) {
    unsigned int u = *(const unsigned int*)&P1[(size_t)csr1[i] * 64 + co];
    a0 += bfl(u);
    a1 += bfh(u);
  }
  float i1 = 1.0f / fmaxf((float)(e1 - b1), 1.0f);
  s0 += a0 * i1;
  s1 += a1 * i1;
  f32x2* hp = (f32x2*)&h[(size_t)w * 64 + co];
  f32x2 hv = *hp;
  hv.x += s0;
  hv.y += s1;
  *hp = hv;
}

__global__ __launch_bounds__(256) void bnstats_kernel(const float* __restrict__ h,
                                                      float* __restrict__ stats, int N) {
  int tid = threadIdx.x;
  int c = tid & 63;
  int part = tid >> 6;
  float s = 0.f, s2 = 0.f;
  for (int r = blockIdx.x * 4 + part; r < N; r += gridDim.x * 4) {
    float v = h[(size_t)r * 64 + c];
    s += v;
    s2 += v * v;
  }
  __shared__ float red[512];
  red[tid] = s;
  red[256 + tid] = s2;
  __syncthreads();
  if (part == 0) {
    s = red[c] + red[64 + c] + red[128 + c] + red[192 + c];
    s2 = red[256 + c] + red[256 + 64 + c] + red[256 + 128 + c] + red[256 + 192 + c];
    atomicAdd(&stats[c], s);
    atomicAdd(&stats[64 + c], s2);
  }
}

// h fp32 -> bf16 activated features (BN + leaky); a/b derived in-block.
__global__ void bnapply_kernel(const float* __restrict__ h, const float* __restrict__ stats,
                               const float* __restrict__ gg, const float* __restrict__ bb,
                               float invN, unsigned short* __restrict__ xo, int N) {
  __shared__ float sa[64], sb[64];
  if (threadIdx.x < 64) {
    int c = threadIdx.x;
    float m = stats[c] * invN;
    float v = stats[64 + c] * invN - m * m;
    float a = gg[c] * rsqrtf(v + 1.0f);
    sa[c] = a;
    sb[c] = bb[c] - m * a;
  }
  __syncthreads();
  int gid = blockIdx.x * blockDim.x + threadIdx.x;
  if (gid >= N * 16) return;
  f32x4 v = ((const f32x4*)h)[gid];
  int c = (gid & 15) * 4;
  u16x4 o;
#pragma unroll
  for (int j = 0; j < 4; ++j) {
    float t = fmaf(sa[c + j], v[j], sb[c + j]);
    o[j] = f2bf(fmaxf(t, 0.01f * t));
  }
  ((u16x4*)xo)[gid] = o;
}

// widening gather: out[row]=[xc[src]||xc[dst]] fp32; 32 threads/row,
// each reads u16x4 (8B) and writes ONE dense f32x4 (16B) -> fully coalesced.
__global__ void gather_kernel(const unsigned short* __restrict__ xc,
                              const int* __restrict__ src0, const int* __restrict__ dst0,
                              const int* __restrict__ src1, const int* __restrict__ dst1,
                              float* __restrict__ out, int E) {
  int gid = blockIdx.x * blockDim.x + threadIdx.x;
  int total = 2 * E * 32;
  if (gid >= total) return;
  int row = gid >> 5, q = gid & 31;
  int e, s, d;
  if (row < E) {
    e = row; s = src0[e]; d = dst0[e];
  } else {
    e = row - E; s = src1[e]; d = dst1[e];
  }
  int node = (q < 16) ? s : d;
  int qq = q & 15;
  u16x4 v = *(const u16x4*)&xc[(size_t)node * 64 + qq * 4];
  f32x4 o;
#pragma unroll
  for (int j = 0; j < 4; ++j) o[j] = bfl((unsigned int)v[j]);
  __builtin_nontemporal_store(o, (f32x4*)out + gid);
}

extern "C" void kernel_launch(void* const* d_in, const int* in_sizes, int n_in,
                              void* d_out, int out_size, void* d_ws, size_t ws_size,
                              hipStream_t stream) {
  const float* x0 = (const float*)d_in[0];
  const int* ei0 = (const int*)d_in[1];
  const int* ei1 = (const int*)d_in[2];
  const float* bn1_g = (const float*)d_in[15];
  const float* bn1_b = (const float*)d_in[16];
  const float* bn2_g = (const float*)d_in[17];
  const float* bn2_b = (const float*)d_in[18];

  const int N = in_sizes[0] / 128;
  const int E = in_sizes[1] / 2;
  const int *src0 = ei0, *dst0 = ei0 + E;
  const int *src1 = ei1, *dst1 = ei1 + E;

  char* wsb = (char*)d_ws;
  size_t off = 0;
  auto alloc = [&](size_t bytes) {
    char* p = wsb + off;
    off = (off + bytes + 255) & ~(size_t)255;
    return (void*)p;
  };
  unsigned short* Wfb1 = (unsigned short*)alloc(192 * 128 * 2);
  unsigned short* Wfb2 = (unsigned short*)alloc(192 * 64 * 2);
  float* stats1 = (float*)alloc(128 * 4);
  float* stats2 = (float*)alloc(128 * 4);
  int* bsum = (int*)alloc(2 * NB_SCAN * 4);
  int* bbase = (int*)alloc(2 * NB_SCAN * 4);
  int* cnt0 = (int*)alloc((size_t)N * 4);
  int* cnt1 = (int*)alloc((size_t)N * 4);
  int* base0 = (int*)alloc(((size_t)N + 1) * 4);
  int* base1 = (int*)alloc(((size_t)N + 1) * 4);
  int* csr0 = (int*)alloc((size_t)E * 4);
  int* csr1 = (int*)alloc((size_t)E * 4);
  float* h = (float*)alloc((size_t)N * 64 * 4);
  float* h2 = (float*)alloc((size_t)N * 64 * 4);
  unsigned short* P0 = (unsigned short*)alloc((size_t)N * 64 * 2);
  unsigned short* P1 = (unsigned short*)alloc((size_t)N * 64 * 2);
  unsigned short* xc2 = (unsigned short*)alloc((size_t)N * 64 * 2);

  const float invN = 1.0f / (float)N;
  const int eg = (E + 255) / 256;
  const int chunk = (N + NB_SCAN - 1) / NB_SCAN;
  const int zb = (N + 255) / 256;

  prep_kernel<<<144 + zb, 256, 0, stream>>>(
      (const float*)d_in[3], (const float*)d_in[4], (const float*)d_in[5],
      (const float*)d_in[6], (const float*)d_in[7], (const float*)d_in[8], Wfb1,
      (const float*)d_in[9], (const float*)d_in[10], (const float*)d_in[11],
      (const float*)d_in[12], (const float*)d_in[13], (const float*)d_in[14], Wfb2,
      cnt0, cnt1, stats1, stats2, N);
  count_both<<<2 * eg, 256, 0, stream>>>(dst0, dst1, cnt0, cnt1, E, eg);
  scanA<<<2 * NB_SCAN, 256, 0, stream>>>(cnt0, cnt1, bsum, N, chunk);
  scanB<<<1, 2 * NB_SCAN, 0, stream>>>(bsum, bbase);
  scanC<<<2 * NB_SCAN, 256, 0, stream>>>(cnt0, cnt1, bbase, base0, base1, N, chunk, E);
  fill_both<<<2 * eg, 256, 0, stream>>>(src0, dst0, base0, cnt0, csr0,
                                        src1, dst1, base1, cnt1, csr1, E, eg);

  const int mmGrid = (N + 63) / 64;
  const int aggGrid = (N * 32 + 255) / 256;

  // layer 1 (A = x0 fp32, cvt inline)
  mm_mfma<128, false><<<mmGrid, 256, 0, stream>>>(x0, Wfb1, nullptr, nullptr, nullptr, 0.f,
                                                  h, P0, P1, N);
  agg_kernel<<<aggGrid, 256, 0, stream>>>(h, P0, P1, csr0, base0, csr1, base1, N);
  bnstats_kernel<<<256, 256, 0, stream>>>(h, stats1, N);

  // layer 2 (A = h fp32, BN1+leaky inline)
  mm_mfma<64, true><<<mmGrid, 256, 0, stream>>>(h, Wfb2, stats1, bn1_g, bn1_b, invN,
                                                h2, P0, P1, N);
  agg_kernel<<<aggGrid, 256, 0, stream>>>(h2, P0, P1, csr0, base0, csr1, base1, N);
  bnstats_kernel<<<256, 256, 0, stream>>>(h2, stats2, N);
  bnapply_kernel<<<(N * 16 + 255) / 256, 256, 0, stream>>>(h2, stats2, bn2_g, bn2_b, invN,
                                                           xc2, N);

  // output gather (dense coalesced widen-copy)
  gather_kernel<<<(2 * E * 32 + 255) / 256, 256, 0, stream>>>(
      xc2, src0, dst0, src1, dst1, (float*)d_out, E);
}

// Round 8
// 318.021 us; speedup vs baseline: 2.2186x; 1.1492x over previous
//
#include <hip/hip_runtime.h>
#include <math.h>

// ---------------------------------------------------------------------------
// HeteroGNN forward. bf16 MFMA GEMM with fp32 A-load + inline cvt (mm1) and
// inline BN+LeakyReLU (mm2); bf16 projected features; CSR mean-agg with
// chunk-4 manual ILP (4 independent gathers in flight); hierarchical scan
// (scanB folded into scanC); BN stats via 256-block atomics; a/b derived
// in-block by consumers; dense widening gather.
//   Wf (192 x F) = [ 0.5*(Wul0@Wd0 + Wul1@Wd1) ; 0.5*Wur0@Ws0 ; 0.5*Wur1@Ws1 ]
//   [h | P0 | P1] = x @ Wf^T   (h fp32, P bf16)
//   h[d] += mean_{csr0[d]} P0[src] + mean_{csr1[d]} P1[src]
//   BN(train, eps=1, biased) + LeakyReLU(0.01)
// ---------------------------------------------------------------------------

typedef float f32x4 __attribute__((ext_vector_type(4)));
typedef float f32x2 __attribute__((ext_vector_type(2)));
typedef short bf16x8 __attribute__((ext_vector_type(8)));
typedef unsigned short u16x4 __attribute__((ext_vector_type(4)));

#define NB_SCAN 64  // scan blocks per edge type

static __device__ __forceinline__ unsigned short f2bf(float f) {
  unsigned int u = __builtin_bit_cast(unsigned int, f);
  unsigned int r = (u + 0x7FFFu + ((u >> 16) & 1u)) >> 16;
  return (unsigned short)r;
}
static __device__ __forceinline__ float bfl(unsigned int u) {
  return __builtin_bit_cast(float, u << 16);
}
static __device__ __forceinline__ float bfh(unsigned int u) {
  return __builtin_bit_cast(float, u & 0xFFFF0000u);
}

// fusew1 (blocks [0,96)), fusew2 ([96,144)), zero cnt+stats ([144, 144+zb))
__global__ void prep_kernel(const float* __restrict__ Wd10, const float* __restrict__ Ws10,
                            const float* __restrict__ Wu10, const float* __restrict__ Wd11,
                            const float* __restrict__ Ws11, const float* __restrict__ Wu11,
                            unsigned short* __restrict__ Wfb1,
                            const float* __restrict__ Wd20, const float* __restrict__ Ws20,
                            const float* __restrict__ Wu20, const float* __restrict__ Wd21,
                            const float* __restrict__ Ws21, const float* __restrict__ Wu21,
                            unsigned short* __restrict__ Wfb2,
                            int* __restrict__ cnt0, int* __restrict__ cnt1,
                            float* __restrict__ s1, float* __restrict__ s2, int N) {
  int b = blockIdx.x;
  if (b >= 144) {
    int g = (b - 144) * 256 + threadIdx.x;
    if (g < N) { cnt0[g] = 0; cnt1[g] = 0; }
    if (g < 128) { s1[g] = 0.f; s2[g] = 0.f; }
    return;
  }
  const float *Wd0, *Ws0, *Wu0, *Wd1, *Ws1, *Wu1;
  unsigned short* Wfb;
  int K, gid;
  if (b < 96) {
    Wd0 = Wd10; Ws0 = Ws10; Wu0 = Wu10; Wd1 = Wd11; Ws1 = Ws11; Wu1 = Wu11;
    Wfb = Wfb1; K = 128;
    gid = b * 256 + threadIdx.x;
  } else {
    Wd0 = Wd20; Ws0 = Ws20; Wu0 = Wu20; Wd1 = Wd21; Ws1 = Ws21; Wu1 = Wu21;
    Wfb = Wfb2; K = 64;
    gid = (b - 96) * 256 + threadIdx.x;
  }
  if (gid >= 192 * K) return;
  int i = gid / K, j = gid - i * K;
  float s = 0.f;
  if (i < 64) {
#pragma unroll 4
    for (int k = 0; k < 64; ++k)
      s += Wu0[i * 128 + k] * Wd0[k * K + j] + Wu1[i * 128 + k] * Wd1[k * K + j];
  } else if (i < 128) {
    int ii = i - 64;
#pragma unroll 4
    for (int k = 0; k < 64; ++k) s += Wu0[ii * 128 + 64 + k] * Ws0[k * K + j];
  } else {
    int ii = i - 128;
#pragma unroll 4
    for (int k = 0; k < 64; ++k) s += Wu1[ii * 128 + 64 + k] * Ws1[k * K + j];
  }
  Wfb[gid] = f2bf(0.5f * s);
}

__global__ void count_both(const int* __restrict__ dst0, const int* __restrict__ dst1,
                           int* __restrict__ cnt0, int* __restrict__ cnt1, int E, int eg) {
  int b = blockIdx.x;
  bool t1 = b >= eg;
  int e = (t1 ? b - eg : b) * 256 + threadIdx.x;
  if (e >= E) return;
  if (t1) atomicAdd(&cnt1[dst1[e]], 1);
  else atomicAdd(&cnt0[dst0[e]], 1);
}

// scan stage A: per-block sums. 2*NB_SCAN blocks.
__global__ __launch_bounds__(256) void scanA(const int* __restrict__ cnt0,
                                             const int* __restrict__ cnt1,
                                             int* __restrict__ bsum, int N, int chunk) {
  int b = blockIdx.x;
  const int* cnt = (b < NB_SCAN) ? cnt0 : cnt1;
  int lb = (b < NB_SCAN) ? b : b - NB_SCAN;
  int lo = lb * chunk, hi = min(lo + chunk, N);
  int s = 0;
  for (int i = lo + threadIdx.x; i < hi; i += 256) s += cnt[i];
  __shared__ int red[256];
  red[threadIdx.x] = s;
  __syncthreads();
  for (int off = 128; off > 0; off >>= 1) {
    if (threadIdx.x < off) red[threadIdx.x] += red[threadIdx.x + off];
    __syncthreads();
  }
  if (threadIdx.x == 0) bsum[b] = red[0];
}

// scan stage C (with inline stage B): per-block local exclusive scan + base.
__global__ __launch_bounds__(256) void scanC(const int* __restrict__ cnt0,
                                             const int* __restrict__ cnt1,
                                             const int* __restrict__ bsum,
                                             int* __restrict__ base0, int* __restrict__ base1,
                                             int N, int chunk, int E) {
  int b = blockIdx.x;
  const int* cnt = (b < NB_SCAN) ? cnt0 : cnt1;
  int* base = (b < NB_SCAN) ? base0 : base1;
  int lb = (b < NB_SCAN) ? b : b - NB_SCAN;
  int lo = lb * chunk, hi = min(lo + chunk, N);
  int t = threadIdx.x;
  // inline scanB: this block's global offset = sum of bsum over its type's
  // preceding blocks (128 values; thread 0 does it serially in LDS).
  __shared__ int lsc[2 * NB_SCAN];
  __shared__ int run0s;
  if (t < 2 * NB_SCAN) lsc[t] = bsum[t];
  __syncthreads();
  if (t == 0) {
    int klo = (b < NB_SCAN) ? 0 : NB_SCAN;
    int r = 0;
    for (int k = klo; k < b; ++k) r += lsc[k];
    run0s = r;
  }
  __syncthreads();
  int v[4];
  int ls = 0;
  int i0 = lo + t * 4;
#pragma unroll
  for (int j = 0; j < 4; ++j) {
    v[j] = (i0 + j < hi) ? cnt[i0 + j] : 0;
    ls += v[j];
  }
  __shared__ int l[256];
  l[t] = ls;
  __syncthreads();
  for (int off = 1; off < 256; off <<= 1) {
    int x = l[t];
    if (t >= off) x += l[t - off];
    __syncthreads();
    l[t] = x;
    __syncthreads();
  }
  int run = run0s + l[t] - ls;
#pragma unroll
  for (int j = 0; j < 4; ++j) {
    if (i0 + j < hi) base[i0 + j] = run;
    run += v[j];
  }
  if (t == 0 && lb == NB_SCAN - 1) base[N] = E;
}

__global__ void fill_both(const int* __restrict__ src0, const int* __restrict__ dst0,
                          const int* __restrict__ base0, int* __restrict__ cnt0,
                          int* __restrict__ csr0,
                          const int* __restrict__ src1, const int* __restrict__ dst1,
                          const int* __restrict__ base1, int* __restrict__ cnt1,
                          int* __restrict__ csr1, int E, int eg) {
  int b = blockIdx.x;
  bool t1 = b >= eg;
  int e = (t1 ? b - eg : b) * 256 + threadIdx.x;
  if (e >= E) return;
  const int* src = t1 ? src1 : src0;
  const int* dst = t1 ? dst1 : dst0;
  const int* base = t1 ? base1 : base0;
  int* cnt = t1 ? cnt1 : cnt0;
  int* csr = t1 ? csr1 : csr0;
  int d = dst[e];
  int p = atomicSub(&cnt[d], 1) - 1;
  csr[base[d] + p] = src[e];
}

// [h|P0|P1] = f(xa)[N,K] @ Wfb[192,K]^T.  A is fp32; BN=false: plain cvt,
// BN=true: y = a*x+b', leaky(0.01) (a,b' derived in-block from raw sums).
// 64 rows/block, 4 waves x 48 cols.
template <int K, bool BN>
__global__ __launch_bounds__(256) void mm_mfma(const float* __restrict__ xa,
                                               const unsigned short* __restrict__ Wfb,
                                               const float* __restrict__ stats,
                                               const float* __restrict__ gg,
                                               const float* __restrict__ bb, float invN,
                                               float* __restrict__ h,
                                               unsigned short* __restrict__ P0,
                                               unsigned short* __restrict__ P1, int N) {
  constexpr int NKS = K / 32;
  __shared__ float sa[64], sb[64];
  int tid = threadIdx.x;
  if constexpr (BN) {
    if (tid < 64) {
      float m = stats[tid] * invN;
      float v = stats[64 + tid] * invN - m * m;
      float a = gg[tid] * rsqrtf(v + 1.0f);
      sa[tid] = a;
      sb[tid] = bb[tid] - m * a;
    }
    __syncthreads();
  }
  int l = tid & 63;
  int wv = tid >> 6;
  int lr = l & 15;
  int lj = l >> 4;
  int brow = blockIdx.x * 64;
  int wcol = wv * 48;

  bf16x8 B[3 * NKS];
#pragma unroll
  for (int ct = 0; ct < 3; ++ct)
#pragma unroll
    for (int ks = 0; ks < NKS; ++ks) {
      int col = wcol + ct * 16 + lr;
      B[ct * NKS + ks] = *(const bf16x8*)&Wfb[(size_t)col * K + ks * 32 + lj * 8];
    }

  f32x4 acc[4][3];
#pragma unroll
  for (int rt = 0; rt < 4; ++rt)
#pragma unroll
    for (int ct = 0; ct < 3; ++ct) acc[rt][ct] = (f32x4){0.f, 0.f, 0.f, 0.f};

#pragma unroll
  for (int ks = 0; ks < NKS; ++ks) {
    int colbase = ks * 32 + lj * 8;
    bf16x8 A[4];
#pragma unroll
    for (int rt = 0; rt < 4; ++rt) {
      int row = brow + rt * 16 + lr;
      if (row >= N) row = N - 1;
      const float* p = &xa[(size_t)row * K + colbase];
      f32x4 v0 = *(const f32x4*)p;
      f32x4 v1 = *(const f32x4*)(p + 4);
      bf16x8 r;
#pragma unroll
      for (int j = 0; j < 4; ++j) {
        float t0 = v0[j], t1 = v1[j];
        if constexpr (BN) {
          int c0 = colbase + j, c1 = colbase + 4 + j;
          t0 = fmaf(sa[c0], t0, sb[c0]);
          t0 = fmaxf(t0, 0.01f * t0);
          t1 = fmaf(sa[c1], t1, sb[c1]);
          t1 = fmaxf(t1, 0.01f * t1);
        }
        r[j] = (short)f2bf(t0);
        r[4 + j] = (short)f2bf(t1);
      }
      A[rt] = r;
    }
#pragma unroll
    for (int rt = 0; rt < 4; ++rt)
#pragma unroll
      for (int ct = 0; ct < 3; ++ct)
        acc[rt][ct] =
            __builtin_amdgcn_mfma_f32_16x16x32_bf16(A[rt], B[ct * NKS + ks], acc[rt][ct], 0, 0, 0);
  }

#pragma unroll
  for (int rt = 0; rt < 4; ++rt)
#pragma unroll
    for (int ct = 0; ct < 3; ++ct) {
      int gct = (wcol >> 4) + ct;
      int sel = gct >> 2;
      int c0 = (gct & 3) * 16 + lr;
#pragma unroll
      for (int r = 0; r < 4; ++r) {
        int row = brow + rt * 16 + lj * 4 + r;
        if (row < N) {
          if (sel == 0) h[(size_t)row * 64 + c0] = acc[rt][ct][r];
          else if (sel == 1) P0[(size_t)row * 64 + c0] = f2bf(acc[rt][ct][r]);
          else P1[(size_t)row * 64 + c0] = f2bf(acc[rt][ct][r]);
        }
      }
    }
}

// half-wave (32 lanes, 2 ch/lane) per dst node. Chunk-4 index loads + 4
// independent gathers in flight + split accumulators for maximum MLP.
__global__ void agg_kernel(float* __restrict__ h, const unsigned short* __restrict__ P0,
                           const unsigned short* __restrict__ P1,
                           const int* __restrict__ csr0, const int* __restrict__ base0,
                           const int* __restrict__ csr1, const int* __restrict__ base1,
                           int N) {
  int gid = blockIdx.x * blockDim.x + threadIdx.x;
  int w = gid >> 5, c = gid & 31;
  if (w >= N) return;
  int co = 2 * c;
  int b0 = base0[w], e0 = base0[w + 1];
  int b1 = base1[w], e1 = base1[w + 1];
  float a0 = 0.f, a1 = 0.f, a2 = 0.f, a3 = 0.f;
  int i = b0;
  for (; i + 4 <= e0; i += 4) {
    int j0 = csr0[i], j1 = csr0[i + 1], j2 = csr0[i + 2], j3 = csr0[i + 3];
    unsigned int u0 = *(const unsigned int*)&P0[(size_t)j0 * 64 + co];
    unsigned int u1 = *(const unsigned int*)&P0[(size_t)j1 * 64 + co];
    unsigned int u2 = *(const unsigned int*)&P0[(size_t)j2 * 64 + co];
    unsigned int u3 = *(const unsigned int*)&P0[(size_t)j3 * 64 + co];
    a0 += bfl(u0); a1 += bfh(u0);
    a2 += bfl(u1); a3 += bfh(u1);
    a0 += bfl(u2); a1 += bfh(u2);
    a2 += bfl(u3); a3 += bfh(u3);
  }
  for (; i < e0; ++i) {
    unsigned int u = *(const unsigned int*)&P0[(size_t)csr0[i] * 64 + co];
    a0 += bfl(u); a1 += bfh(u);
  }
  float i0 = 1.0f / fmaxf((float)(e0 - b0), 1.0f);
  float s0 = (a0 + a2) * i0, s1 = (a1 + a3) * i0;
  a0 = 0.f; a1 = 0.f; a2 = 0.f; a3 = 0.f;
  i = b1;
  for (; i + 4 <= e1; i += 4) {
    int j0 = csr1[i], j1 = csr1[i + 1], j2 = csr1[i + 2], j3 = csr1[i + 3];
    unsigned int u0 = *(const unsigned int*)&P1[(size_t)j0 * 64 + co];
    unsigned int u1 = *(const unsigned int*)&P1[(size_t)j1 * 64 + co];
    unsigned int u2 = *(const unsigned int*)&P1[(size_t)j2 * 64 + co];
    unsigned int u3 = *(const unsigned int*)&P1[(size_t)j3 * 64 + co];
    a0 += bfl(u0); a1 += bfh(u0);
    a2 += bfl(u1); a3 += bfh(u1);
    a0 += bfl(u2); a1 += bfh(u2);
    a2 += bfl(u3); a3 += bfh(u3);
  }
  for (; i < e1; ++i) {
    unsigned int u = *(const unsigned int*)&P1[(size_t)csr1[i] * 64 + co];
    a0 += bfl(u); a1 += bfh(u);
  }
  float i1 = 1.0f / fmaxf((float)(e1 - b1), 1.0f);
  s0 += (a0 + a2) * i1;
  s1 += (a1 + a3) * i1;
  f32x2* hp = (f32x2*)&h[(size_t)w * 64 + co];
  f32x2 hv = *hp;
  hv.x += s0;
  hv.y += s1;
  *hp = hv;
}

__global__ __launch_bounds__(256) void bnstats_kernel(const float* __restrict__ h,
                                                      float* __restrict__ stats, int N) {
  int tid = threadIdx.x;
  int c = tid & 63;
  int part = tid >> 6;
  float s = 0.f, s2 = 0.f;
  for (int r = blockIdx.x * 4 + part; r < N; r += gridDim.x * 4) {
    float v = h[(size_t)r * 64 + c];
    s += v;
    s2 += v * v;
  }
  __shared__ float red[512];
  red[tid] = s;
  red[256 + tid] = s2;
  __syncthreads();
  if (part == 0) {
    s = red[c] + red[64 + c] + red[128 + c] + red[192 + c];
    s2 = red[256 + c] + red[256 + 64 + c] + red[256 + 128 + c] + red[256 + 192 + c];
    atomicAdd(&stats[c], s);
    atomicAdd(&stats[64 + c], s2);
  }
}

// h fp32 -> bf16 activated features (BN + leaky); a/b derived in-block.
__global__ void bnapply_kernel(const float* __restrict__ h, const float* __restrict__ stats,
                               const float* __restrict__ gg, const float* __restrict__ bb,
                               float invN, unsigned short* __restrict__ xo, int N) {
  __shared__ float sa[64], sb[64];
  if (threadIdx.x < 64) {
    int c = threadIdx.x;
    float m = stats[c] * invN;
    float v = stats[64 + c] * invN - m * m;
    float a = gg[c] * rsqrtf(v + 1.0f);
    sa[c] = a;
    sb[c] = bb[c] - m * a;
  }
  __syncthreads();
  int gid = blockIdx.x * blockDim.x + threadIdx.x;
  if (gid >= N * 16) return;
  f32x4 v = ((const f32x4*)h)[gid];
  int c = (gid & 15) * 4;
  u16x4 o;
#pragma unroll
  for (int j = 0; j < 4; ++j) {
    float t = fmaf(sa[c + j], v[j], sb[c + j]);
    o[j] = f2bf(fmaxf(t, 0.01f * t));
  }
  ((u16x4*)xo)[gid] = o;
}

// widening gather: out[row]=[xc[src]||xc[dst]] fp32; 32 threads/row,
// each reads u16x4 (8B) and writes ONE dense f32x4 (16B) -> fully coalesced.
__global__ void gather_kernel(const unsigned short* __restrict__ xc,
                              const int* __restrict__ src0, const int* __restrict__ dst0,
                              const int* __restrict__ src1, const int* __restrict__ dst1,
                              float* __restrict__ out, int E) {
  int gid = blockIdx.x * blockDim.x + threadIdx.x;
  int total = 2 * E * 32;
  if (gid >= total) return;
  int row = gid >> 5, q = gid & 31;
  int e, s, d;
  if (row < E) {
    e = row; s = src0[e]; d = dst0[e];
  } else {
    e = row - E; s = src1[e]; d = dst1[e];
  }
  int node = (q < 16) ? s : d;
  int qq = q & 15;
  u16x4 v = *(const u16x4*)&xc[(size_t)node * 64 + qq * 4];
  f32x4 o;
#pragma unroll
  for (int j = 0; j < 4; ++j) o[j] = bfl((unsigned int)v[j]);
  __builtin_nontemporal_store(o, (f32x4*)out + gid);
}

extern "C" void kernel_launch(void* const* d_in, const int* in_sizes, int n_in,
                              void* d_out, int out_size, void* d_ws, size_t ws_size,
                              hipStream_t stream) {
  const float* x0 = (const float*)d_in[0];
  const int* ei0 = (const int*)d_in[1];
  const int* ei1 = (const int*)d_in[2];
  const float* bn1_g = (const float*)d_in[15];
  const float* bn1_b = (const float*)d_in[16];
  const float* bn2_g = (const float*)d_in[17];
  const float* bn2_b = (const float*)d_in[18];

  const int N = in_sizes[0] / 128;
  const int E = in_sizes[1] / 2;
  const int *src0 = ei0, *dst0 = ei0 + E;
  const int *src1 = ei1, *dst1 = ei1 + E;

  char* wsb = (char*)d_ws;
  size_t off = 0;
  auto alloc = [&](size_t bytes) {
    char* p = wsb + off;
    off = (off + bytes + 255) & ~(size_t)255;
    return (void*)p;
  };
  unsigned short* Wfb1 = (unsigned short*)alloc(192 * 128 * 2);
  unsigned short* Wfb2 = (unsigned short*)alloc(192 * 64 * 2);
  float* stats1 = (float*)alloc(128 * 4);
  float* stats2 = (float*)alloc(128 * 4);
  int* bsum = (int*)alloc(2 * NB_SCAN * 4);
  int* cnt0 = (int*)alloc((size_t)N * 4);
  int* cnt1 = (int*)alloc((size_t)N * 4);
  int* base0 = (int*)alloc(((size_t)N + 1) * 4);
  int* base1 = (int*)alloc(((size_t)N + 1) * 4);
  int* csr0 = (int*)alloc((size_t)E * 4);
  int* csr1 = (int*)alloc((size_t)E * 4);
  float* h = (float*)alloc((size_t)N * 64 * 4);
  float* h2 = (float*)alloc((size_t)N * 64 * 4);
  unsigned short* P0 = (unsigned short*)alloc((size_t)N * 64 * 2);
  unsigned short* P1 = (unsigned short*)alloc((size_t)N * 64 * 2);
  unsigned short* xc2 = (unsigned short*)alloc((size_t)N * 64 * 2);

  const float invN = 1.0f / (float)N;
  const int eg = (E + 255) / 256;
  const int chunk = (N + NB_SCAN - 1) / NB_SCAN;
  const int zb = (N + 255) / 256;

  prep_kernel<<<144 + zb, 256, 0, stream>>>(
      (const float*)d_in[3], (const float*)d_in[4], (const float*)d_in[5],
      (const float*)d_in[6], (const float*)d_in[7], (const float*)d_in[8], Wfb1,
      (const float*)d_in[9], (const float*)d_in[10], (const float*)d_in[11],
      (const float*)d_in[12], (const float*)d_in[13], (const float*)d_in[14], Wfb2,
      cnt0, cnt1, stats1, stats2, N);
  count_both<<<2 * eg, 256, 0, stream>>>(dst0, dst1, cnt0, cnt1, E, eg);
  scanA<<<2 * NB_SCAN, 256, 0, stream>>>(cnt0, cnt1, bsum, N, chunk);
  scanC<<<2 * NB_SCAN, 256, 0, stream>>>(cnt0, cnt1, bsum, base0, base1, N, chunk, E);
  fill_both<<<2 * eg, 256, 0, stream>>>(src0, dst0, base0, cnt0, csr0,
                                        src1, dst1, base1, cnt1, csr1, E, eg);

  const int mmGrid = (N + 63) / 64;
  const int aggGrid = (N * 32 + 255) / 256;

  // layer 1 (A = x0 fp32, cvt inline)
  mm_mfma<128, false><<<mmGrid, 256, 0, stream>>>(x0, Wfb1, nullptr, nullptr, nullptr, 0.f,
                                                  h, P0, P1, N);
  agg_kernel<<<aggGrid, 256, 0, stream>>>(h, P0, P1, csr0, base0, csr1, base1, N);
  bnstats_kernel<<<256, 256, 0, stream>>>(h, stats1, N);

  // layer 2 (A = h fp32, BN1+leaky inline)
  mm_mfma<64, true><<<mmGrid, 256, 0, stream>>>(h, Wfb2, stats1, bn1_g, bn1_b, invN,
                                                h2, P0, P1, N);
  agg_kernel<<<aggGrid, 256, 0, stream>>>(h2, P0, P1, csr0, base0, csr1, base1, N);
  bnstats_kernel<<<256, 256, 0, stream>>>(h2, stats2, N);
  bnapply_kernel<<<(N * 16 + 255) / 256, 256, 0, stream>>>(h2, stats2, bn2_g, bn2_b, invN,
                                                           xc2, N);

  // output gather (dense coalesced widen-copy)
  gather_kernel<<<(2 * E * 32 + 255) / 256, 256, 0, stream>>>(
      xc2, src0, dst0, src1, dst1, (float*)d_out, E);
}